// Round 1
// baseline (53.728 us; speedup 1.0000x reference)
//
#include <hip/hip_runtime.h>

// GraphVolterraLayer: N_S=64, N_T=32, N_EFF=2048, K_T1=K_T2=8, BATCH=16.
// Kronecker-factored evaluation, one fused kernel.
// Block (b,iT): computes out[b, iS*32+iT] for all iS in [0,64).
//
//  S_b   = reshape(s[b], 64x32)
//  shat  = U_G^T S_b U_P_T                       (64x32)
//  H1    = h1c @ Ub1^T                            (64x32)
//  z1    = U_G^T (H1 .* shat) U_P_T               (64x32), we need column iT
//  Gm[kS,p] = sum_kT shat[kS,kT]*U_P_T[iT,kT]*U_P_T[kT,p]   (64x8)
//  E     = H_S .* (Gm Hc Gm^T)                    (64x64)
//  z2[iS] = u_iS^T E u_iS,  u_iS = U_G[iS,:]
//  out[b,(iS,iT)] = h0[(iS,iT)] + z1[iS,iT] + z2[iS]

__global__ __launch_bounds__(256) void volterra_fused(
    const float* __restrict__ s,    // (16,2048)
    const float* __restrict__ UG,   // (64,64)
    const float* __restrict__ UPT,  // (32,32)
    const float* __restrict__ h0,   // (2048,)
    const float* __restrict__ h1c,  // (64,8)
    const float* __restrict__ HS,   // (64,64)
    const float* __restrict__ Hc,   // (8,8)
    float* __restrict__ out)        // (16,2048)
{
  const int blk = blockIdx.x;
  const int b   = blk >> 5;
  const int iT  = blk & 31;
  const int t   = threadIdx.x;

  __shared__ float sUG[64][65];    // padded: bank = (row+col)%32
  __shared__ float sUPT[32][33];
  __shared__ float sS[64][33];     // S_b, later overwritten with shat
  __shared__ float sT[64][33];     // temp (UG^T S), later (UG^T (H1.*shat))
  __shared__ float sH1[64][33];
  __shared__ float sH1c[64][9];
  __shared__ float sw[8][33];      // sw[p][kT] = UPT[iT][kT]*UPT[kT][p]
  __shared__ float sHc[8][9];
  __shared__ float sGm[64][9];
  __shared__ float sA[64][9];      // Gm @ Hc
  __shared__ float sE[64][65];
  __shared__ float sZ1[64];

  // ---- loads ----
  for (int i = t; i < 64 * 64; i += 256) sUG[i >> 6][i & 63] = UG[i];
  for (int i = t; i < 32 * 32; i += 256) sUPT[i >> 5][i & 31] = UPT[i];
  for (int i = t; i < 64 * 32; i += 256) sS[i >> 5][i & 31] = s[b * 2048 + i];
  for (int i = t; i < 64 * 8;  i += 256) sH1c[i >> 3][i & 7] = h1c[i];
  if (t < 64) sHc[t >> 3][t & 7] = Hc[t];
  {
    const int p = t >> 5, k = t & 31;   // all 256 threads: p in [0,8)
    sw[p][k] = UPT[iT * 32 + k] * UPT[k * 32 + p];
  }
  __syncthreads();

  // ---- sT = UG^T @ S ;  sH1 = h1c @ Ub1^T (same (row,col) layout) ----
  for (int o = t; o < 2048; o += 256) {
    const int r = o >> 5, c = o & 31;
    float a1 = 0.f, a2 = 0.f;
    #pragma unroll 8
    for (int kS = 0; kS < 64; ++kS) a1 += sUG[kS][r] * sS[kS][c];
    #pragma unroll
    for (int p = 0; p < 8; ++p) a2 += sH1c[r][p] * sUPT[c][p];
    sT[r][c]  = a1;
    sH1[r][c] = a2;
  }
  __syncthreads();

  // ---- shat = sT @ UPT  (write into sS; no reader of old sS in this phase) ----
  for (int o = t; o < 2048; o += 256) {
    const int r = o >> 5, c = o & 31;
    float a = 0.f;
    #pragma unroll 8
    for (int k = 0; k < 32; ++k) a += sT[r][k] * sUPT[k][c];
    sS[r][c] = a;
  }
  __syncthreads();

  // ---- sT = UG^T @ (H1 .* shat) ;  Gm[kS][p] = sum_k shat[kS][k]*sw[p][k] ----
  for (int o = t; o < 2048; o += 256) {
    const int r = o >> 5, c = o & 31;
    float a = 0.f;
    #pragma unroll 8
    for (int kS = 0; kS < 64; ++kS) a += sUG[kS][r] * (sH1[kS][c] * sS[kS][c]);
    sT[r][c] = a;
  }
  for (int o = t; o < 512; o += 256) {
    const int kS = o >> 3, p = o & 7;
    float a = 0.f;
    #pragma unroll 8
    for (int k = 0; k < 32; ++k) a += sS[kS][k] * sw[p][k];
    sGm[kS][p] = a;
  }
  __syncthreads();

  // ---- z1 column iT ;  A = Gm @ Hc ----
  if (t < 64) {
    float a = 0.f;
    #pragma unroll 8
    for (int k = 0; k < 32; ++k) a += sT[t][k] * sUPT[k][iT];
    sZ1[t] = a;
  }
  for (int o = t; o < 512; o += 256) {
    const int kS = o >> 3, p = o & 7;
    float a = 0.f;
    #pragma unroll
    for (int q = 0; q < 8; ++q) a += sGm[kS][q] * sHc[q][p];
    sA[kS][p] = a;
  }
  __syncthreads();

  // ---- E = HS .* (A @ Gm^T) ----
  for (int o = t; o < 4096; o += 256) {
    const int kS = o >> 6, lS = o & 63;
    float a = 0.f;
    #pragma unroll
    for (int p = 0; p < 8; ++p) a += sA[kS][p] * sGm[lS][p];
    sE[kS][lS] = a * HS[o];
  }
  __syncthreads();

  // ---- z2[iS] = sum_{kS,lS} UG[iS][kS]*E[kS][lS]*UG[iS][lS] ----
  // 4 threads per iS, each covers 16 kS rows; butterfly-reduce the quad.
  const int iS = t >> 2, q = t & 3;
  float acc = 0.f;
  for (int j = 0; j < 16; ++j) {
    const int kS = q * 16 + j;
    float tv = 0.f;
    #pragma unroll 8
    for (int lS = 0; lS < 64; ++lS) tv += sE[kS][lS] * sUG[iS][lS];
    acc += sUG[iS][kS] * tv;
  }
  acc += __shfl_xor(acc, 1);
  acc += __shfl_xor(acc, 2);
  if (q == 0) {
    const int col = iS * 32 + iT;
    out[b * 2048 + col] = h0[col] + sZ1[iS] + acc;
  }
}

extern "C" void kernel_launch(void* const* d_in, const int* in_sizes, int n_in,
                              void* d_out, int out_size, void* d_ws, size_t ws_size,
                              hipStream_t stream) {
  const float* s   = (const float*)d_in[0];  // (16,2048)
  const float* UG  = (const float*)d_in[1];  // (64,64)
  const float* UPT = (const float*)d_in[2];  // (32,32)
  const float* h0  = (const float*)d_in[3];  // (2048,)
  const float* h1c = (const float*)d_in[4];  // (64,8)
  const float* HS  = (const float*)d_in[5];  // (64,64)
  const float* Hc  = (const float*)d_in[6];  // (8,8)
  float* out = (float*)d_out;

  volterra_fused<<<512, 256, 0, stream>>>(s, UG, UPT, h0, h1c, HS, Hc, out);
}

// Round 2
// 23.184 us; speedup vs baseline: 2.3175x; 2.3175x over previous
//
#include <hip/hip_runtime.h>

// GraphVolterraLayer: N_S=64, N_T=32, N_EFF=2048, K_T1=K_T2=8, BATCH=16.
//
// Two-kernel Kronecker-factored plan:
//  k1 (grid 16b x 4 chunks): per b  shat = UG^T S_b UPT   (64x32) -> ws
//                                    wmat = (H1 .* shat) @ UPT     -> ws
//        (z1[b,iS,iT] = sum_kS UG[kS,iS] * wmat[kS,iT])
//  k2 (grid 16b x 32 iT): Gm = (shat .* UPT[iT,:]) @ W   (64x8)
//                          A = Gm Hc ; E = HS .* (A Gm^T) (64x64)
//                          z2[iS] = u_iS^T E u_iS  via F-GEMM (64^3, reg-tiled)
//                          out = h0 + z1col + z2
// ws floats: [0,32768) shat[16][64][32]; [32768,65536) wmat[16][64][32]

__global__ __launch_bounds__(256) void k1_prepare(
    const float* __restrict__ s, const float* __restrict__ UG,
    const float* __restrict__ UPT, const float* __restrict__ h1c,
    float* __restrict__ ws)
{
  const int b  = blockIdx.x >> 2;
  const int ch = blockIdx.x & 3;          // rows [16ch, 16ch+16)
  const int t  = threadIdx.x;

  __shared__ float sS[64][33];
  __shared__ float sUPT[32][33];
  __shared__ float sUGc[64][17];          // UG[kS][16ch+rl]
  __shared__ float sh1c[16][9];
  __shared__ float sT1[16][33];
  __shared__ float sY[16][33];

  for (int o = t; o < 2048; o += 256) sS[o >> 5][o & 31] = s[b * 2048 + o];
  for (int o = t; o < 1024; o += 256) sUPT[o >> 5][o & 31] = UPT[o];
  for (int o = t; o < 1024; o += 256) {
    int kS = o >> 4, rl = o & 15;
    sUGc[kS][rl] = UG[kS * 64 + ch * 16 + rl];
  }
  if (t < 128) sh1c[t >> 3][t & 7] = h1c[ch * 128 + t];
  __syncthreads();

  // T1[rl][c] = sum_kS UG[kS][16ch+rl] * S[kS][c]
  for (int o = t; o < 512; o += 256) {
    int rl = o >> 5, c = o & 31;
    float a = 0.f;
    #pragma unroll 8
    for (int kS = 0; kS < 64; ++kS) a += sUGc[kS][rl] * sS[kS][c];
    sT1[rl][c] = a;
  }
  __syncthreads();

  // shat rows -> ws ;  Y = (h1c @ Ub1^T) .* shat
  for (int o = t; o < 512; o += 256) {
    int rl = o >> 5, c = o & 31;
    float sh = 0.f, h1 = 0.f;
    #pragma unroll 8
    for (int k = 0; k < 32; ++k) sh += sT1[rl][k] * sUPT[k][c];
    #pragma unroll
    for (int p = 0; p < 8; ++p) h1 += sh1c[rl][p] * sUPT[c][p];
    ws[b * 2048 + (ch * 16 + rl) * 32 + c] = sh;
    sY[rl][c] = sh * h1;
  }
  __syncthreads();

  // wmat[r][iT] = sum_k Y[r][k] * UPT[k][iT]
  for (int o = t; o < 512; o += 256) {
    int rl = o >> 5, c = o & 31;
    float a = 0.f;
    #pragma unroll 8
    for (int k = 0; k < 32; ++k) a += sY[rl][k] * sUPT[k][c];
    ws[32768 + b * 2048 + (ch * 16 + rl) * 32 + c] = a;
  }
}

// chunk-swizzle for [64][64] fp32 LDS arrays: row r, element c lives at
// word r*64 + (((c>>2)+(r>>2))&15)*4 + (c&3). 16B chunks stay intact
// (float4-readable); rows at stride 4 or 16 map to distinct bank quads.
__device__ __forceinline__ int swz(int r, int c) {
  return r * 64 + ((((c >> 2) + (r >> 2)) & 15) << 2) + (c & 3);
}

__global__ __launch_bounds__(256) void k2_main(
    const float* __restrict__ ws, const float* __restrict__ UG,
    const float* __restrict__ UPT, const float* __restrict__ h0,
    const float* __restrict__ HS, const float* __restrict__ Hc,
    float* __restrict__ out)
{
  const int b  = blockIdx.x >> 5;
  const int iT = blockIdx.x & 31;
  const int t  = threadIdx.x;

  __shared__ float sShat[64][33];
  __shared__ __align__(16) float sUGf[4096];   // swizzled UG rows
  __shared__ __align__(16) float sEf[4096];    // swizzled E rows
  __shared__ float sGm[64][9];
  __shared__ float sA[64][9];
  __shared__ float vw[32][9];                  // vw[k][p] = UPT[iT,k]*UPT[k,p]
  __shared__ float sHc[8][9];
  __shared__ float wvec[64];                   // wmat[b][:,iT]
  __shared__ float z1c[64];
  __shared__ float zpart[16][65];

  // ---- P0: stage ----
  for (int o = t; o < 2048; o += 256) sShat[o >> 5][o & 31] = ws[b * 2048 + o];
  {
    const float4* ug4 = (const float4*)UG;
    float4* dst = (float4*)sUGf;
    for (int o4 = t; o4 < 1024; o4 += 256) {
      int r = o4 >> 4, c4 = o4 & 15;
      dst[r * 16 + ((c4 + (r >> 2)) & 15)] = ug4[o4];
    }
  }
  { int k = t >> 3, p = t & 7; vw[k][p] = UPT[iT * 32 + k] * UPT[k * 32 + p]; }
  if (t < 64) sHc[t >> 3][t & 7] = Hc[t];
  if (t < 64) wvec[t] = ws[32768 + b * 2048 + t * 32 + iT];
  __syncthreads();

  // ---- P1: Gm[kS][p] = sum_k shat[kS][k]*vw[k][p]  (2 rows/thread) ----
  {
    int kS = t >> 3, p = t & 7;
    float a1 = 0.f, a2 = 0.f;
    #pragma unroll 8
    for (int k = 0; k < 32; ++k) {
      float w = vw[k][p];
      a1 += sShat[kS][k] * w;
      a2 += sShat[kS + 32][k] * w;
    }
    sGm[kS][p] = a1;
    sGm[kS + 32][p] = a2;
  }
  __syncthreads();

  // ---- P2: A = Gm @ Hc ; z1 column ----
  {
    int kS = t >> 3, p = t & 7;
    float a1 = 0.f, a2 = 0.f;
    #pragma unroll
    for (int q = 0; q < 8; ++q) {
      float h = sHc[q][p];
      a1 += sGm[kS][q] * h;
      a2 += sGm[kS + 32][q] * h;
    }
    sA[kS][p] = a1;
    sA[kS + 32][p] = a2;
  }
  if (t < 64) {
    float a = 0.f;
    #pragma unroll 8
    for (int kS = 0; kS < 64; ++kS) a += sUGf[swz(kS, t)] * wvec[kS];
    z1c[t] = a;
  }
  __syncthreads();

  // ---- P3: E[kS][lS] = HS[kS,lS] * sum_p A[kS][p]*Gm[lS][p]  (swizzled store)
  for (int j = 0; j < 16; ++j) {
    int o = t + 256 * j;
    int kS = o >> 6, lS = o & 63;
    float a = 0.f;
    #pragma unroll
    for (int p = 0; p < 8; ++p) a += sA[kS][p] * sGm[lS][p];
    sEf[swz(kS, lS)] = a * HS[o];
  }
  __syncthreads();

  // ---- P4: F = E @ UG^T register-tiled; fuse z2 partials ----
  const int ty = t >> 4, tx = t & 15;  // within wave: 4 ty-values, 16 tx-values
  float acc[4][4] = {};
  for (int k4 = 0; k4 < 16; ++k4) {
    float4 ea[4], ub[4];
    const int posE = ((k4 + ty) & 15) << 2;
    #pragma unroll
    for (int i = 0; i < 4; ++i)
      ea[i] = *(const float4*)&sEf[(4 * ty + i) * 64 + posE];
    const int posU = ((k4 + tx) & 15) << 2;
    #pragma unroll
    for (int j = 0; j < 4; ++j)
      ub[j] = *(const float4*)&sUGf[(4 * tx + j) * 64 + posU];
    #pragma unroll
    for (int i = 0; i < 4; ++i)
      #pragma unroll
      for (int j = 0; j < 4; ++j)
        acc[i][j] += ea[i].x * ub[j].x + ea[i].y * ub[j].y +
                     ea[i].z * ub[j].z + ea[i].w * ub[j].w;
  }
  // zpart[ty][c] = sum_i UG[c][4ty+i] * F[4ty+i][c]
  #pragma unroll
  for (int j = 0; j < 4; ++j) {
    int c = 4 * tx + j;
    float zp = 0.f;
    #pragma unroll
    for (int i = 0; i < 4; ++i) {
      int addr = c * 64 + (((ty + tx) & 15) << 2) + i;  // swz(c, 4ty+i)
      zp += sUGf[addr] * acc[i][j];
    }
    zpart[ty][c] = zp;
  }
  __syncthreads();

  // ---- P5: reduce + write ----
  if (t < 64) {
    float z2 = 0.f;
    #pragma unroll
    for (int u = 0; u < 16; ++u) z2 += zpart[u][t];
    int col = t * 32 + iT;
    out[b * 2048 + col] = h0[col] + z1c[t] + z2;
  }
}

extern "C" void kernel_launch(void* const* d_in, const int* in_sizes, int n_in,
                              void* d_out, int out_size, void* d_ws, size_t ws_size,
                              hipStream_t stream) {
  const float* s   = (const float*)d_in[0];  // (16,2048)
  const float* UG  = (const float*)d_in[1];  // (64,64)
  const float* UPT = (const float*)d_in[2];  // (32,32)
  const float* h0  = (const float*)d_in[3];  // (2048,)
  const float* h1c = (const float*)d_in[4];  // (64,8)
  const float* HS  = (const float*)d_in[5];  // (64,64)
  const float* Hc  = (const float*)d_in[6];  // (8,8)
  float* out = (float*)d_out;
  float* ws  = (float*)d_ws;                 // needs 65536 floats = 256 KiB

  k1_prepare<<<64, 256, 0, stream>>>(s, UG, UPT, h1c, ws);
  k2_main<<<512, 256, 0, stream>>>(ws, UG, UPT, h0, HS, Hc, out);
}